// Round 17
// baseline (606.885 us; speedup 1.0000x reference)
//
#include <hip/hip_runtime.h>
#include <hip/hip_fp16.h>

constexpr int HI = 256, WI = 256;   // reg_feat spatial
constexpr int HO = 512, WO = 512;   // upsampled spatial
constexpr int CI = 32;              // feat channels
constexpr int CK = 49;              // 7x7 unfold channels

// ---- ws layout (float offsets) --------------------------------------------
constexpr size_t OFF_WPC = 0;        // w2 fp16 frags: 13*4*64 uint4 = 13312 f32
constexpr size_t OFF_B2P = 26624;    // padded b2 [64]
constexpr size_t OFF_WPB = 26688;    // w1 frags: 7*2*4*64 uint4 = 14336 f32
constexpr size_t OFF_B1P = 41024;    // padded b1 [64]
constexpr size_t OFF_WPA = 41088;    // wt frags: 4cls*4tap*2s*2mf*64 uint4 = 16384 f32
constexpr size_t OFF_F0  = 57472;    // f0h,f0l bf16 planes [512][512][32] each
constexpr size_t OFF_XPP = OFF_F0 + (size_t)HO * WO * CI;      // xph,xpl planes
constexpr size_t OFF_FLP = OFF_XPP + (size_t)258 * 258 * 32;   // flowp f32 [2][518][518]

constexpr int FP_W = 518;            // padded flow row (512 + 3 + 3)
constexpr int XP_W = 258;            // padded x row (256 + 1 + 1)

using bf16x8 = __attribute__((ext_vector_type(8))) short;
using f16x8  = __attribute__((ext_vector_type(8))) _Float16;
using f32x4  = __attribute__((ext_vector_type(4))) float;

__device__ inline unsigned bf_rne(float x) {           // fp32 -> bf16 bits (RNE)
    unsigned u = __float_as_uint(x);
    return (u + 0x7FFFu + ((u >> 16) & 1u)) >> 16;
}
__device__ inline unsigned short h_rne(float x) {      // fp32 -> fp16 bits (RNE)
    return __half_as_ushort(__float2half(x));
}

union FragU { uint4 q; bf16x8 v; unsigned u[4]; };
union FragH { uint4 q; f16x8 v; };

// ---------------------------------------------------------------------------
// kPP: fused padding kernel (R16 version, unchanged). x -> separate hi/lo
// bf16 planes xph/xpl; flow -> flowp zero-padded.
// ---------------------------------------------------------------------------
__global__ void kPP(const float* __restrict__ x, const float* __restrict__ flow,
                    unsigned short* __restrict__ xph, unsigned short* __restrict__ xpl,
                    float* __restrict__ flowp)
{
    const int bid = blockIdx.x;
    if (bid < XP_W) {
        const int yp = bid;
        const int y  = yp - 1;
        for (int xpc = threadIdx.x; xpc < XP_W; xpc += 256) {
            const int xc = xpc - 1;
            const size_t po = ((size_t)yp * XP_W + xpc) * 32;   // ushort index
            uint4* dh = reinterpret_cast<uint4*>(xph + po);
            uint4* dl = reinterpret_cast<uint4*>(xpl + po);
            if ((unsigned)y < 256u && (unsigned)xc < 256u) {
                const float* src = x + y * 256 + xc;
                unsigned hw[16], lw[16];
                #pragma unroll
                for (int c2 = 0; c2 < 16; ++c2) {
                    const float v0 = src[(size_t)(2 * c2) * 65536];
                    const float v1 = src[(size_t)(2 * c2 + 1) * 65536];
                    const unsigned h0 = bf_rne(v0), h1 = bf_rne(v1);
                    const unsigned l0 = bf_rne(v0 - __uint_as_float(h0 << 16));
                    const unsigned l1 = bf_rne(v1 - __uint_as_float(h1 << 16));
                    hw[c2] = (h1 << 16) | h0;
                    lw[c2] = (l1 << 16) | l0;
                }
                const uint4* hq = reinterpret_cast<const uint4*>(hw);
                const uint4* lq = reinterpret_cast<const uint4*>(lw);
                #pragma unroll
                for (int r = 0; r < 4; ++r) { dh[r] = hq[r]; dl[r] = lq[r]; }
            } else {
                #pragma unroll
                for (int r = 0; r < 4; ++r) {
                    dh[r] = make_uint4(0u, 0u, 0u, 0u);
                    dl[r] = make_uint4(0u, 0u, 0u, 0u);
                }
            }
        }
    } else {
        const int idx = (bid - XP_W) * 256 + threadIdx.x;
        if (idx >= 2 * FP_W * FP_W) return;
        const int p  = idx / (FP_W * FP_W);
        const int q  = idx - p * (FP_W * FP_W);
        const int hh = q / FP_W;
        const int ww = q - hh * FP_W;
        float v = 0.f;
        const int hs = hh - 3, wsx = ww - 3;
        if ((unsigned)hs < (unsigned)HO && (unsigned)wsx < (unsigned)WO)
            v = flow[p * (HO * WO) + hs * WO + wsx];
        flowp[idx] = v;
    }
}

// ---------------------------------------------------------------------------
// repack: kA frags + stage-1 frags unchanged (split-bf16); stage-2 frags now
// FP16 single-set: wpC[(c*4+mf)*64+lane], same k-enumeration as R12-R16
// (kg=4c+g -> oct=kg/7, t=kg%7; elem j -> i=oct*8+j).
// ---------------------------------------------------------------------------
__global__ void repack(const float* __restrict__ wt,
                       const float* __restrict__ w1, const float* __restrict__ b1,
                       const float* __restrict__ w2, const float* __restrict__ b2,
                       uint4* __restrict__ wpA, uint4* __restrict__ wpB,
                       float* __restrict__ b1p, uint4* __restrict__ wpC,
                       float* __restrict__ b2p)
{
    const int j = blockIdx.x * 256 + threadIdx.x;
    if (j < 64) {
        b2p[j] = (j < CK) ? b2[j] : 1e18f;
        b1p[j] = (j < CK) ? b1[j] : 0.f;
    }
    if (j < 4 * 4 * 2 * 2 * 64) {           // kA (unchanged)
        const int lane = j & 63;
        const int mf   = (j >> 6) & 1;
        const int s    = (j >> 7) & 1;
        const int tap  = (j >> 8) & 3;
        const int cls  = j >> 10;
        const int ohpar = cls >> 1, par = cls & 1;
        const int a = tap >> 1, d = tap & 1;
        const int kh = (ohpar ? 0 : 1) + 2 * a;
        const int kw = (par ? 0 : 1) + 2 * d;
        const int o = mf * 16 + (lane & 15);
        unsigned b[8];
        #pragma unroll
        for (int jj = 0; jj < 8; ++jj) {
            const int i = (lane >> 4) * 8 + jj;
            const float v = wt[((i * 32 + o) * 4 + kh) * 4 + kw];
            const unsigned hi = bf_rne(v);
            b[jj] = (s == 0) ? hi : bf_rne(v - __uint_as_float(hi << 16));
        }
        uint4 q;
        q.x = (b[1] << 16) | b[0];
        q.y = (b[3] << 16) | b[2];
        q.z = (b[5] << 16) | b[4];
        q.w = (b[7] << 16) | b[6];
        wpA[j] = q;
    }
    if (j < 7 * 2 * 4 * 64) {               // stage-1: chunk t, k = i (unchanged)
        const int t    = j >> 9;
        const int s    = (j >> 8) & 1;
        const int mf   = (j >> 6) & 3;
        const int lane = j & 63;
        const int o = mf * 16 + (lane & 15);
        unsigned b[8];
        #pragma unroll
        for (int jj = 0; jj < 8; ++jj) {
            const int i = (lane >> 4) * 8 + jj;
            float v = (o < CK) ? w1[o * 224 + i * 7 + t] : 0.f;
            const unsigned hi = bf_rne(v);
            b[jj] = (s == 0) ? hi : bf_rne(v - __uint_as_float(hi << 16));
        }
        uint4 q;
        q.x = (b[1] << 16) | b[0];
        q.y = (b[3] << 16) | b[2];
        q.z = (b[5] << 16) | b[4];
        q.w = (b[7] << 16) | b[6];
        wpB[((t * 2 + s) * 4 + mf) * 64 + lane] = q;
    }
    if (j < 13 * 4 * 64) {                  // stage-2 FP16 encoding
        const int c    = j >> 8;
        const int mf   = (j >> 6) & 3;
        const int lane = j & 63;
        const int o   = mf * 16 + (lane & 15);
        const int kg  = 4 * c + (lane >> 4);
        const int oct = kg / 7;
        const int t   = kg - 7 * oct;
        unsigned short b[8];
        #pragma unroll
        for (int jj = 0; jj < 8; ++jj) {
            const int i = oct * 8 + jj;
            float v = 0.f;
            if (kg < CK && o < CK && i < CK) v = w2[o * 343 + i * 7 + t];
            b[jj] = h_rne(v);
        }
        uint4 q;
        q.x = ((unsigned)b[1] << 16) | b[0];
        q.y = ((unsigned)b[3] << 16) | b[2];
        q.z = ((unsigned)b[5] << 16) | b[4];
        q.w = ((unsigned)b[7] << 16) | b[6];
        wpC[(c * 4 + mf) * 64 + lane] = q;
    }
}

// ---------------------------------------------------------------------------
// kA: ConvTranspose2d via split-bf16 MFMA (R16 version, unchanged).
// ---------------------------------------------------------------------------
__global__ __launch_bounds__(256, 4)
void kA(const unsigned short* __restrict__ xph, const unsigned short* __restrict__ xpl,
        const uint4* __restrict__ wpA, const float* __restrict__ bt,
        unsigned short* __restrict__ f0h, unsigned short* __restrict__ f0l)
{
    __shared__ unsigned ep[4][64 * 36];     // [px][hi0..15 | lo16..31 | pad]

    const int tid  = threadIdx.x;
    const int oh   = blockIdx.x >> 1;
    const int half = blockIdx.x & 1;
    const int wv   = tid >> 6;
    const int lane = tid & 63;
    const int col  = lane & 15;
    const int g    = lane >> 4;
    const int par  = wv >> 1;
    const int n0   = half * 128 + (wv & 1) * 64;

    const int ohpar = oh & 1;
    const int kh0   = ohpar ? 0 : 1;
    const int ihA   = (oh + 1 - kh0) >> 1;
    const int cls   = ohpar * 2 + par;
    const int ioff  = par ? 2 : 1;

    f32x4 acc[2][4];
    #pragma unroll
    for (int mf = 0; mf < 2; ++mf)
        #pragma unroll
        for (int nf = 0; nf < 4; ++nf)
            acc[mf][nf] = (f32x4){0.f, 0.f, 0.f, 0.f};

    #pragma unroll
    for (int a = 0; a < 2; ++a) {
        const int rowbase = (ihA + 1 - a) * XP_W;
        #pragma unroll
        for (int d = 0; d < 2; ++d) {
            bf16x8 Bh[4], Bl[4];
            #pragma unroll
            for (int nf = 0; nf < 4; ++nf) {
                const size_t base =
                    ((size_t)(rowbase + n0 + nf * 16 + col + ioff - d)) * 32 + g * 8;
                FragU fh, fl;
                fh.q = *reinterpret_cast<const uint4*>(xph + base);
                fl.q = *reinterpret_cast<const uint4*>(xpl + base);
                Bh[nf] = fh.v;
                Bl[nf] = fl.v;
            }
            const int tap = a * 2 + d;
            #pragma unroll
            for (int mf = 0; mf < 2; ++mf) {
                FragU ah, al;
                ah.q = wpA[(((cls * 4 + tap) * 2 + 0) * 2 + mf) * 64 + lane];
                al.q = wpA[(((cls * 4 + tap) * 2 + 1) * 2 + mf) * 64 + lane];
                #pragma unroll
                for (int nf = 0; nf < 4; ++nf) {
                    acc[mf][nf] = __builtin_amdgcn_mfma_f32_16x16x32_bf16(ah.v, Bh[nf], acc[mf][nf], 0, 0, 0);
                    acc[mf][nf] = __builtin_amdgcn_mfma_f32_16x16x32_bf16(ah.v, Bl[nf], acc[mf][nf], 0, 0, 0);
                    acc[mf][nf] = __builtin_amdgcn_mfma_f32_16x16x32_bf16(al.v, Bh[nf], acc[mf][nf], 0, 0, 0);
                }
            }
        }
    }

    unsigned* myep = ep[wv];
    #pragma unroll
    for (int mf = 0; mf < 2; ++mf)
        #pragma unroll
        for (int nf = 0; nf < 4; ++nf) {
            unsigned hh[4], ll[4];
            #pragma unroll
            for (int r = 0; r < 4; ++r) {
                const int ch = mf * 16 + g * 4 + r;
                const float v = acc[mf][nf][r] + bt[ch];
                hh[r] = bf_rne(v);
                ll[r] = bf_rne(v - __uint_as_float(hh[r] << 16));
            }
            unsigned* row = myep + (nf * 16 + col) * 36;
            const int cp = mf * 8 + g * 2;
            row[cp]          = (hh[1] << 16) | hh[0];
            row[cp + 1]      = (hh[3] << 16) | hh[2];
            row[16 + cp]     = (ll[1] << 16) | ll[0];
            row[16 + cp + 1] = (ll[3] << 16) | ll[2];
        }
    // same-wave LDS RAW: compiler orders via lgkmcnt; no barrier needed

    const int ow = 2 * (n0 + lane) + par;
    const size_t po = ((size_t)oh * WO + ow) * 32;   // ushort index
    uint4* dh = reinterpret_cast<uint4*>(f0h + po);
    uint4* dl = reinterpret_cast<uint4*>(f0l + po);
    const uint4* sh = reinterpret_cast<const uint4*>(myep + lane * 36);
    const uint4* sl = reinterpret_cast<const uint4*>(myep + lane * 36 + 16);
    #pragma unroll
    for (int u = 0; u < 4; ++u) { dh[u] = sh[u]; dl[u] = sl[u]; }
}

// ---------------------------------------------------------------------------
// kBC: FUSED stage B + stage C. Stage 1 unchanged (split-bf16, direct plane
// loads). f1 row now staged as a SINGLE FP16 LDS plane; stage 2 = ONE
// mfma_f32_16x16x32_f16 per (chunk, nf) — 3x fewer MFMAs, half the LDS
// reads. LDS 38.4K -> ~23.2K => 6 blocks/CU.
// ---------------------------------------------------------------------------
__global__ __launch_bounds__(256, 6)
void kBC(const unsigned short* __restrict__ f0h, const unsigned short* __restrict__ f0l,
         const uint4* __restrict__ wpB, const float* __restrict__ b1p,
         const uint4* __restrict__ wpC, const float* __restrict__ b2p,
         const float* __restrict__ flowp, float* __restrict__ out)
{
    __shared__ uint4 L4[134 * 7];           // fp16 plane, rows of 7 uint4 (56 ch)
    __shared__ float gm[4][128];            // per-wave per-pixel min partials
    __shared__ float dvp[4][128];           // per-wave softmax partials
    __shared__ float sxp[4][128];
    __shared__ float syp[4][128];
    unsigned* Lp = reinterpret_cast<unsigned*>(L4);

    // bijective XCD swizzle: 2048 blocks = 8 XCDs x 256 contiguous
    const int bid = ((blockIdx.x & 7) << 8) + (blockIdx.x >> 3);
    const int h   = bid >> 2;
    const int w0  = (bid & 3) << 7;

    const int tid  = threadIdx.x;
    const int wv   = tid >> 6;
    const int lane = tid & 63;
    const int col  = lane & 15;
    const int g    = lane >> 4;

    // ---- stage 1: f1 row h, cols w0-3 .. w0+140 (9 frags of 16) ------------
    const int nfr = (wv == 3) ? 3 : 2;
    const int fid0 = wv, fid1 = wv + 4, fid2 = 8;

    f32x4 acc1[3][4];
    #pragma unroll
    for (int fi = 0; fi < 3; ++fi)
        #pragma unroll
        for (int mf = 0; mf < 4; ++mf)
            acc1[fi][mf] = (f32x4){0.f, 0.f, 0.f, 0.f};

    #pragma unroll
    for (int t = 0; t < 7; ++t) {
        const int hr = h + t - 3;
        if ((unsigned)hr < (unsigned)HO) {
            FragU ah[4], al[4];
            #pragma unroll
            for (int mf = 0; mf < 4; ++mf) {
                ah[mf].q = wpB[((t * 2 + 0) * 4 + mf) * 64 + lane];
                al[mf].q = wpB[((t * 2 + 1) * 4 + mf) * 64 + lane];
            }
            #pragma unroll
            for (int fi = 0; fi < 3; ++fi) {
                if (fi < nfr) {
                    const int f  = (fi == 0) ? fid0 : (fi == 1) ? fid1 : fid2;
                    const int wc = w0 - 3 + f * 16 + col;
                    const int wcc = min(max(wc, 0), WO - 1);
                    const bool valid = ((unsigned)wc < (unsigned)WO);
                    const size_t base = ((size_t)hr * WO + wcc) * 32 + g * 8;
                    FragU fh, fl;
                    fh.q = *reinterpret_cast<const uint4*>(f0h + base);
                    fl.q = *reinterpret_cast<const uint4*>(f0l + base);
                    if (!valid) {
                        fh.q = make_uint4(0u, 0u, 0u, 0u);
                        fl.q = make_uint4(0u, 0u, 0u, 0u);
                    }
                    #pragma unroll
                    for (int mf = 0; mf < 4; ++mf) {
                        acc1[fi][mf] = __builtin_amdgcn_mfma_f32_16x16x32_bf16(ah[mf].v, fh.v, acc1[fi][mf], 0, 0, 0);
                        acc1[fi][mf] = __builtin_amdgcn_mfma_f32_16x16x32_bf16(ah[mf].v, fl.v, acc1[fi][mf], 0, 0, 0);
                        acc1[fi][mf] = __builtin_amdgcn_mfma_f32_16x16x32_bf16(al[mf].v, fh.v, acc1[fi][mf], 0, 0, 0);
                    }
                }
            }
        }
    }

    // write f1 row into the FP16 plane; out-of-image columns store ZERO.
    #pragma unroll
    for (int fi = 0; fi < 3; ++fi) {
        if (fi < nfr) {
            const int f = (fi == 0) ? fid0 : (fi == 1) ? fid1 : fid2;
            const int q = f * 16 + col;
            const int wc = w0 - 3 + q;
            const bool vcol = ((unsigned)wc < (unsigned)WO);
            if (q < 134) {
                #pragma unroll
                for (int mf = 0; mf < 4; ++mf) {
                    if (mf < 3 || g < 2) {          // ch 56..63 don't exist
                        const int chb = mf * 16 + g * 4;
                        unsigned short hv[4];
                        #pragma unroll
                        for (int r = 0; r < 4; ++r) {
                            const float v = vcol ? (acc1[fi][mf][r] + b1p[chb + r]) : 0.f;
                            hv[r] = h_rne(v);
                        }
                        const int ip = mf * 8 + g * 2;
                        Lp[q * 28 + ip]     = ((unsigned)hv[1] << 16) | hv[0];
                        Lp[q * 28 + ip + 1] = ((unsigned)hv[3] << 16) | hv[2];
                    }
                }
            }
        }
    }
    __syncthreads();

    // ---- stage 2 (fp16): wave wv = mf; all 128 px (nf=0..7) ----------------
    const int mf2 = wv;
    f32x4 acc[8];
    #pragma unroll
    for (int nf = 0; nf < 8; ++nf)
        acc[nf] = (f32x4){0.f, 0.f, 0.f, 0.f};

    #pragma unroll
    for (int c = 0; c < 13; ++c) {
        const int kg  = 4 * c + g;
        const int oct = (kg * 37) >> 8;     // kg/7 for kg<=51
        const int t   = kg - 7 * oct;
        FragH ah;
        ah.q = wpC[(c * 4 + mf2) * 64 + lane];
        const int bqb = (col + t) * 7 + oct;
        #pragma unroll
        for (int nf = 0; nf < 8; ++nf) {
            FragH bh;
            bh.q = L4[bqb + nf * 112];      // +16 px * 7 uint4
            acc[nf] = __builtin_amdgcn_mfma_f32_16x16x32_f16(ah.v, bh.v, acc[nf], 0, 0, 0);
        }
    }

    // ---- epilogue: sq, cross-wave min, exp-weighted flow average -----------
    float bb2[4];
    #pragma unroll
    for (int r = 0; r < 4; ++r)
        bb2[r] = b2p[mf2 * 16 + g * 4 + r];

    #pragma unroll
    for (int nf = 0; nf < 8; ++nf)
        #pragma unroll
        for (int r = 0; r < 4; ++r) {
            const float fv = acc[nf][r] + bb2[r];
            acc[nf][r] = fv * fv;
        }

    #pragma unroll
    for (int nf = 0; nf < 8; ++nf) {
        float m = fminf(fminf(acc[nf][0], acc[nf][1]), fminf(acc[nf][2], acc[nf][3]));
        m = fminf(m, __shfl_xor(m, 16));
        m = fminf(m, __shfl_xor(m, 32));
        if (lane < 16) gm[wv][nf * 16 + lane] = m;
    }
    __syncthreads();

    float M[8];
    #pragma unroll
    for (int nf = 0; nf < 8; ++nf)
        M[nf] = fminf(fminf(gm[0][nf * 16 + col], gm[1][nf * 16 + col]),
                      fminf(gm[2][nf * 16 + col], gm[3][nf * 16 + col]));

    const float* fpx = flowp + (size_t)h * FP_W + (w0 + col);
    const float* fpy = fpx + (size_t)FP_W * FP_W;
    float dv[8], sx[8], sy[8];
    #pragma unroll
    for (int nf = 0; nf < 8; ++nf) { dv[nf] = 0.f; sx[nf] = 0.f; sy[nf] = 0.f; }

    #pragma unroll
    for (int r = 0; r < 4; ++r) {
        const int ch = mf2 * 16 + g * 4 + r;
        int ki = (ch * 37) >> 8;            // floor(ch/7) for ch<64
        int kj = ch - 7 * ki;
        ki = min(ki, 6);                    // pad channels: d==0, clamp for safety
        kj = min(kj, 6);
        const int off = ki * FP_W + kj;
        #pragma unroll
        for (int nf = 0; nf < 8; ++nf) {
            const float d = __expf(M[nf] - acc[nf][r]);
            dv[nf] += d;
            sx[nf] += d * fpx[off + nf * 16];
            sy[nf] += d * fpy[off + nf * 16];
        }
    }

    #pragma unroll
    for (int nf = 0; nf < 8; ++nf) {
        float d = dv[nf], x = sx[nf], y = sy[nf];
        d += __shfl_xor(d, 16);  x += __shfl_xor(x, 16);  y += __shfl_xor(y, 16);
        d += __shfl_xor(d, 32);  x += __shfl_xor(x, 32);  y += __shfl_xor(y, 32);
        if (lane < 16) {
            dvp[wv][nf * 16 + lane] = d;
            sxp[wv][nf * 16 + lane] = x;
            syp[wv][nf * 16 + lane] = y;
        }
    }
    __syncthreads();

    if (tid < 128) {
        const float D = dvp[0][tid] + dvp[1][tid] + dvp[2][tid] + dvp[3][tid];
        const float X = sxp[0][tid] + sxp[1][tid] + sxp[2][tid] + sxp[3][tid];
        const float Y = syp[0][tid] + syp[1][tid] + syp[2][tid] + syp[3][tid];
        const int w = w0 + tid;
        out[(size_t)h * WO + w]                   = X / D;
        out[(size_t)HO * WO + (size_t)h * WO + w] = Y / D;
    }
}

// ---------------------------------------------------------------------------
extern "C" void kernel_launch(void* const* d_in, const int* in_sizes, int n_in,
                              void* d_out, int out_size, void* d_ws, size_t ws_size,
                              hipStream_t stream) {
    const float* reg_feat = (const float*)d_in[0];
    const float* flow     = (const float*)d_in[1];
    const float* wt       = (const float*)d_in[2];
    const float* bt       = (const float*)d_in[3];
    const float* w1       = (const float*)d_in[4];
    const float* b1       = (const float*)d_in[5];
    const float* w2       = (const float*)d_in[6];
    const float* b2       = (const float*)d_in[7];
    float* out = (float*)d_out;
    (void)in_sizes; (void)n_in; (void)out_size; (void)ws_size;

    float*          ws   = (float*)d_ws;
    uint4*          wpC  = (uint4*)(ws + OFF_WPC);
    float*          b2p  = ws + OFF_B2P;
    uint4*          wpB  = (uint4*)(ws + OFF_WPB);
    float*          b1p  = ws + OFF_B1P;
    uint4*          wpA  = (uint4*)(ws + OFF_WPA);
    unsigned short* f0h  = (unsigned short*)(ws + OFF_F0);
    unsigned short* f0l  = f0h + (size_t)HO * WO * CI;
    unsigned short* xph  = (unsigned short*)(ws + OFF_XPP);
    unsigned short* xpl  = xph + (size_t)XP_W * XP_W * 32;
    float*          flowp = ws + OFF_FLP;

    repack<<<26, 256, 0, stream>>>(wt, w1, b1, w2, b2, wpA, wpB, b1p, wpC, b2p);

    const int padBlocks = XP_W + (2 * FP_W * FP_W + 255) / 256;
    for (int b = 0; b < 4; ++b) {
        const float* xb  = reg_feat + (size_t)b * CI * HI * WI;
        const float* flb = flow     + (size_t)b * 2 * HO * WO;
        float*       ob  = out      + (size_t)b * 2 * HO * WO;
        kPP<<<padBlocks, 256, 0, stream>>>(xb, flb, xph, xpl, flowp);
        kA<<<1024, 256, 0, stream>>>(xph, xpl, wpA, bt, f0h, f0l);
        kBC<<<2048, 256, 0, stream>>>(f0h, f0l, wpB, b1p, wpC, b2p, flowp, ob);
    }
}

// Round 18
// 353.792 us; speedup vs baseline: 1.7154x; 1.7154x over previous
//
#include <hip/hip_runtime.h>
#include <hip/hip_fp16.h>

constexpr int HI = 256, WI = 256;   // reg_feat spatial
constexpr int HO = 512, WO = 512;   // upsampled spatial
constexpr int CI = 32;              // feat channels
constexpr int CK = 49;              // 7x7 unfold channels

// ---- ws layout (float offsets) --------------------------------------------
constexpr size_t OFF_WPC = 0;        // w2 fp16 frags: 13*4*64 uint4 = 13312 f32
constexpr size_t OFF_B2P = 26624;    // padded b2 [64]
constexpr size_t OFF_WPB = 26688;    // w1 frags: 7*2*4*64 uint4 = 14336 f32
constexpr size_t OFF_B1P = 41024;    // padded b1 [64]
constexpr size_t OFF_WPA = 41088;    // wt frags: 4cls*4tap*2s*2mf*64 uint4 = 16384 f32
constexpr size_t OFF_F0  = 57472;    // f0h,f0l bf16 planes [512][512][32] each
constexpr size_t OFF_XPP = OFF_F0 + (size_t)HO * WO * CI;      // xph,xpl planes
constexpr size_t OFF_FLP = OFF_XPP + (size_t)258 * 258 * 32;   // flowp f32 [2][518][518]

constexpr int FP_W = 518;            // padded flow row (512 + 3 + 3)
constexpr int XP_W = 258;            // padded x row (256 + 1 + 1)

using bf16x8 = __attribute__((ext_vector_type(8))) short;
using f16x8  = __attribute__((ext_vector_type(8))) _Float16;
using f32x4  = __attribute__((ext_vector_type(4))) float;

__device__ inline unsigned bf_rne(float x) {           // fp32 -> bf16 bits (RNE)
    unsigned u = __float_as_uint(x);
    return (u + 0x7FFFu + ((u >> 16) & 1u)) >> 16;
}
__device__ inline unsigned short h_rne(float x) {      // fp32 -> fp16 bits (RNE)
    return __half_as_ushort(__float2half(x));
}

union FragU { uint4 q; bf16x8 v; unsigned u[4]; };
union FragH { uint4 q; f16x8 v; };

// ---------------------------------------------------------------------------
// kPP: fused padding kernel (R16 version, unchanged). x -> separate hi/lo
// bf16 planes xph/xpl; flow -> flowp zero-padded.
// ---------------------------------------------------------------------------
__global__ void kPP(const float* __restrict__ x, const float* __restrict__ flow,
                    unsigned short* __restrict__ xph, unsigned short* __restrict__ xpl,
                    float* __restrict__ flowp)
{
    const int bid = blockIdx.x;
    if (bid < XP_W) {
        const int yp = bid;
        const int y  = yp - 1;
        for (int xpc = threadIdx.x; xpc < XP_W; xpc += 256) {
            const int xc = xpc - 1;
            const size_t po = ((size_t)yp * XP_W + xpc) * 32;   // ushort index
            uint4* dh = reinterpret_cast<uint4*>(xph + po);
            uint4* dl = reinterpret_cast<uint4*>(xpl + po);
            if ((unsigned)y < 256u && (unsigned)xc < 256u) {
                const float* src = x + y * 256 + xc;
                unsigned hw[16], lw[16];
                #pragma unroll
                for (int c2 = 0; c2 < 16; ++c2) {
                    const float v0 = src[(size_t)(2 * c2) * 65536];
                    const float v1 = src[(size_t)(2 * c2 + 1) * 65536];
                    const unsigned h0 = bf_rne(v0), h1 = bf_rne(v1);
                    const unsigned l0 = bf_rne(v0 - __uint_as_float(h0 << 16));
                    const unsigned l1 = bf_rne(v1 - __uint_as_float(h1 << 16));
                    hw[c2] = (h1 << 16) | h0;
                    lw[c2] = (l1 << 16) | l0;
                }
                const uint4* hq = reinterpret_cast<const uint4*>(hw);
                const uint4* lq = reinterpret_cast<const uint4*>(lw);
                #pragma unroll
                for (int r = 0; r < 4; ++r) { dh[r] = hq[r]; dl[r] = lq[r]; }
            } else {
                #pragma unroll
                for (int r = 0; r < 4; ++r) {
                    dh[r] = make_uint4(0u, 0u, 0u, 0u);
                    dl[r] = make_uint4(0u, 0u, 0u, 0u);
                }
            }
        }
    } else {
        const int idx = (bid - XP_W) * 256 + threadIdx.x;
        if (idx >= 2 * FP_W * FP_W) return;
        const int p  = idx / (FP_W * FP_W);
        const int q  = idx - p * (FP_W * FP_W);
        const int hh = q / FP_W;
        const int ww = q - hh * FP_W;
        float v = 0.f;
        const int hs = hh - 3, wsx = ww - 3;
        if ((unsigned)hs < (unsigned)HO && (unsigned)wsx < (unsigned)WO)
            v = flow[p * (HO * WO) + hs * WO + wsx];
        flowp[idx] = v;
    }
}

// ---------------------------------------------------------------------------
// repack (R17 version, unchanged): kA frags + stage-1 frags split-bf16;
// stage-2 frags FP16 single-set wpC[(c*4+mf)*64+lane].
// ---------------------------------------------------------------------------
__global__ void repack(const float* __restrict__ wt,
                       const float* __restrict__ w1, const float* __restrict__ b1,
                       const float* __restrict__ w2, const float* __restrict__ b2,
                       uint4* __restrict__ wpA, uint4* __restrict__ wpB,
                       float* __restrict__ b1p, uint4* __restrict__ wpC,
                       float* __restrict__ b2p)
{
    const int j = blockIdx.x * 256 + threadIdx.x;
    if (j < 64) {
        b2p[j] = (j < CK) ? b2[j] : 1e18f;
        b1p[j] = (j < CK) ? b1[j] : 0.f;
    }
    if (j < 4 * 4 * 2 * 2 * 64) {           // kA (unchanged)
        const int lane = j & 63;
        const int mf   = (j >> 6) & 1;
        const int s    = (j >> 7) & 1;
        const int tap  = (j >> 8) & 3;
        const int cls  = j >> 10;
        const int ohpar = cls >> 1, par = cls & 1;
        const int a = tap >> 1, d = tap & 1;
        const int kh = (ohpar ? 0 : 1) + 2 * a;
        const int kw = (par ? 0 : 1) + 2 * d;
        const int o = mf * 16 + (lane & 15);
        unsigned b[8];
        #pragma unroll
        for (int jj = 0; jj < 8; ++jj) {
            const int i = (lane >> 4) * 8 + jj;
            const float v = wt[((i * 32 + o) * 4 + kh) * 4 + kw];
            const unsigned hi = bf_rne(v);
            b[jj] = (s == 0) ? hi : bf_rne(v - __uint_as_float(hi << 16));
        }
        uint4 q;
        q.x = (b[1] << 16) | b[0];
        q.y = (b[3] << 16) | b[2];
        q.z = (b[5] << 16) | b[4];
        q.w = (b[7] << 16) | b[6];
        wpA[j] = q;
    }
    if (j < 7 * 2 * 4 * 64) {               // stage-1: chunk t, k = i (unchanged)
        const int t    = j >> 9;
        const int s    = (j >> 8) & 1;
        const int mf   = (j >> 6) & 3;
        const int lane = j & 63;
        const int o = mf * 16 + (lane & 15);
        unsigned b[8];
        #pragma unroll
        for (int jj = 0; jj < 8; ++jj) {
            const int i = (lane >> 4) * 8 + jj;
            float v = (o < CK) ? w1[o * 224 + i * 7 + t] : 0.f;
            const unsigned hi = bf_rne(v);
            b[jj] = (s == 0) ? hi : bf_rne(v - __uint_as_float(hi << 16));
        }
        uint4 q;
        q.x = (b[1] << 16) | b[0];
        q.y = (b[3] << 16) | b[2];
        q.z = (b[5] << 16) | b[4];
        q.w = (b[7] << 16) | b[6];
        wpB[((t * 2 + s) * 4 + mf) * 64 + lane] = q;
    }
    if (j < 13 * 4 * 64) {                  // stage-2 FP16 encoding
        const int c    = j >> 8;
        const int mf   = (j >> 6) & 3;
        const int lane = j & 63;
        const int o   = mf * 16 + (lane & 15);
        const int kg  = 4 * c + (lane >> 4);
        const int oct = kg / 7;
        const int t   = kg - 7 * oct;
        unsigned short b[8];
        #pragma unroll
        for (int jj = 0; jj < 8; ++jj) {
            const int i = oct * 8 + jj;
            float v = 0.f;
            if (kg < CK && o < CK && i < CK) v = w2[o * 343 + i * 7 + t];
            b[jj] = h_rne(v);
        }
        uint4 q;
        q.x = ((unsigned)b[1] << 16) | b[0];
        q.y = ((unsigned)b[3] << 16) | b[2];
        q.z = ((unsigned)b[5] << 16) | b[4];
        q.w = ((unsigned)b[7] << 16) | b[6];
        wpC[(c * 4 + mf) * 64 + lane] = q;
    }
}

// ---------------------------------------------------------------------------
// kA: ConvTranspose2d via split-bf16 MFMA (R16 version, unchanged).
// ---------------------------------------------------------------------------
__global__ __launch_bounds__(256, 4)
void kA(const unsigned short* __restrict__ xph, const unsigned short* __restrict__ xpl,
        const uint4* __restrict__ wpA, const float* __restrict__ bt,
        unsigned short* __restrict__ f0h, unsigned short* __restrict__ f0l)
{
    __shared__ unsigned ep[4][64 * 36];     // [px][hi0..15 | lo16..31 | pad]

    const int tid  = threadIdx.x;
    const int oh   = blockIdx.x >> 1;
    const int half = blockIdx.x & 1;
    const int wv   = tid >> 6;
    const int lane = tid & 63;
    const int col  = lane & 15;
    const int g    = lane >> 4;
    const int par  = wv >> 1;
    const int n0   = half * 128 + (wv & 1) * 64;

    const int ohpar = oh & 1;
    const int kh0   = ohpar ? 0 : 1;
    const int ihA   = (oh + 1 - kh0) >> 1;
    const int cls   = ohpar * 2 + par;
    const int ioff  = par ? 2 : 1;

    f32x4 acc[2][4];
    #pragma unroll
    for (int mf = 0; mf < 2; ++mf)
        #pragma unroll
        for (int nf = 0; nf < 4; ++nf)
            acc[mf][nf] = (f32x4){0.f, 0.f, 0.f, 0.f};

    #pragma unroll
    for (int a = 0; a < 2; ++a) {
        const int rowbase = (ihA + 1 - a) * XP_W;
        #pragma unroll
        for (int d = 0; d < 2; ++d) {
            bf16x8 Bh[4], Bl[4];
            #pragma unroll
            for (int nf = 0; nf < 4; ++nf) {
                const size_t base =
                    ((size_t)(rowbase + n0 + nf * 16 + col + ioff - d)) * 32 + g * 8;
                FragU fh, fl;
                fh.q = *reinterpret_cast<const uint4*>(xph + base);
                fl.q = *reinterpret_cast<const uint4*>(xpl + base);
                Bh[nf] = fh.v;
                Bl[nf] = fl.v;
            }
            const int tap = a * 2 + d;
            #pragma unroll
            for (int mf = 0; mf < 2; ++mf) {
                FragU ah, al;
                ah.q = wpA[(((cls * 4 + tap) * 2 + 0) * 2 + mf) * 64 + lane];
                al.q = wpA[(((cls * 4 + tap) * 2 + 1) * 2 + mf) * 64 + lane];
                #pragma unroll
                for (int nf = 0; nf < 4; ++nf) {
                    acc[mf][nf] = __builtin_amdgcn_mfma_f32_16x16x32_bf16(ah.v, Bh[nf], acc[mf][nf], 0, 0, 0);
                    acc[mf][nf] = __builtin_amdgcn_mfma_f32_16x16x32_bf16(ah.v, Bl[nf], acc[mf][nf], 0, 0, 0);
                    acc[mf][nf] = __builtin_amdgcn_mfma_f32_16x16x32_bf16(al.v, Bh[nf], acc[mf][nf], 0, 0, 0);
                }
            }
        }
    }

    unsigned* myep = ep[wv];
    #pragma unroll
    for (int mf = 0; mf < 2; ++mf)
        #pragma unroll
        for (int nf = 0; nf < 4; ++nf) {
            unsigned hh[4], ll[4];
            #pragma unroll
            for (int r = 0; r < 4; ++r) {
                const int ch = mf * 16 + g * 4 + r;
                const float v = acc[mf][nf][r] + bt[ch];
                hh[r] = bf_rne(v);
                ll[r] = bf_rne(v - __uint_as_float(hh[r] << 16));
            }
            unsigned* row = myep + (nf * 16 + col) * 36;
            const int cp = mf * 8 + g * 2;
            row[cp]          = (hh[1] << 16) | hh[0];
            row[cp + 1]      = (hh[3] << 16) | hh[2];
            row[16 + cp]     = (ll[1] << 16) | ll[0];
            row[16 + cp + 1] = (ll[3] << 16) | ll[2];
        }
    // same-wave LDS RAW: compiler orders via lgkmcnt; no barrier needed

    const int ow = 2 * (n0 + lane) + par;
    const size_t po = ((size_t)oh * WO + ow) * 32;   // ushort index
    uint4* dh = reinterpret_cast<uint4*>(f0h + po);
    uint4* dl = reinterpret_cast<uint4*>(f0l + po);
    const uint4* sh = reinterpret_cast<const uint4*>(myep + lane * 36);
    const uint4* sl = reinterpret_cast<const uint4*>(myep + lane * 36 + 16);
    #pragma unroll
    for (int u = 0; u < 4; ++u) { dh[u] = sh[u]; dl[u] = sl[u]; }
}

// ---------------------------------------------------------------------------
// kBC: FUSED stage B + stage C. Stage 1 split-bf16 (direct plane loads);
// f1 staged as a SINGLE FP16 LDS plane; stage 2 = ONE mfma_f32_16x16x32_f16
// per (chunk, nf). launch_bounds(256,4) — R17's (256,6) VGPR cap caused
// catastrophic scratch spill (FETCH 110MB / WRITE 203MB); 4 gives the
// compiler the same headroom that compiled R16 at 64 VGPR spill-free.
// ---------------------------------------------------------------------------
__global__ __launch_bounds__(256, 4)
void kBC(const unsigned short* __restrict__ f0h, const unsigned short* __restrict__ f0l,
         const uint4* __restrict__ wpB, const float* __restrict__ b1p,
         const uint4* __restrict__ wpC, const float* __restrict__ b2p,
         const float* __restrict__ flowp, float* __restrict__ out)
{
    __shared__ uint4 L4[134 * 7];           // fp16 plane, rows of 7 uint4 (56 ch)
    __shared__ float gm[4][128];            // per-wave per-pixel min partials
    __shared__ float dvp[4][128];           // per-wave softmax partials
    __shared__ float sxp[4][128];
    __shared__ float syp[4][128];
    unsigned* Lp = reinterpret_cast<unsigned*>(L4);

    // bijective XCD swizzle: 2048 blocks = 8 XCDs x 256 contiguous
    const int bid = ((blockIdx.x & 7) << 8) + (blockIdx.x >> 3);
    const int h   = bid >> 2;
    const int w0  = (bid & 3) << 7;

    const int tid  = threadIdx.x;
    const int wv   = tid >> 6;
    const int lane = tid & 63;
    const int col  = lane & 15;
    const int g    = lane >> 4;

    // ---- stage 1: f1 row h, cols w0-3 .. w0+140 (9 frags of 16) ------------
    const int nfr = (wv == 3) ? 3 : 2;
    const int fid0 = wv, fid1 = wv + 4, fid2 = 8;

    f32x4 acc1[3][4];
    #pragma unroll
    for (int fi = 0; fi < 3; ++fi)
        #pragma unroll
        for (int mf = 0; mf < 4; ++mf)
            acc1[fi][mf] = (f32x4){0.f, 0.f, 0.f, 0.f};

    #pragma unroll
    for (int t = 0; t < 7; ++t) {
        const int hr = h + t - 3;
        if ((unsigned)hr < (unsigned)HO) {
            FragU ah[4], al[4];
            #pragma unroll
            for (int mf = 0; mf < 4; ++mf) {
                ah[mf].q = wpB[((t * 2 + 0) * 4 + mf) * 64 + lane];
                al[mf].q = wpB[((t * 2 + 1) * 4 + mf) * 64 + lane];
            }
            #pragma unroll
            for (int fi = 0; fi < 3; ++fi) {
                if (fi < nfr) {
                    const int f  = (fi == 0) ? fid0 : (fi == 1) ? fid1 : fid2;
                    const int wc = w0 - 3 + f * 16 + col;
                    const int wcc = min(max(wc, 0), WO - 1);
                    const bool valid = ((unsigned)wc < (unsigned)WO);
                    const size_t base = ((size_t)hr * WO + wcc) * 32 + g * 8;
                    FragU fh, fl;
                    fh.q = *reinterpret_cast<const uint4*>(f0h + base);
                    fl.q = *reinterpret_cast<const uint4*>(f0l + base);
                    if (!valid) {
                        fh.q = make_uint4(0u, 0u, 0u, 0u);
                        fl.q = make_uint4(0u, 0u, 0u, 0u);
                    }
                    #pragma unroll
                    for (int mf = 0; mf < 4; ++mf) {
                        acc1[fi][mf] = __builtin_amdgcn_mfma_f32_16x16x32_bf16(ah[mf].v, fh.v, acc1[fi][mf], 0, 0, 0);
                        acc1[fi][mf] = __builtin_amdgcn_mfma_f32_16x16x32_bf16(ah[mf].v, fl.v, acc1[fi][mf], 0, 0, 0);
                        acc1[fi][mf] = __builtin_amdgcn_mfma_f32_16x16x32_bf16(al[mf].v, fh.v, acc1[fi][mf], 0, 0, 0);
                    }
                }
            }
        }
    }

    // write f1 row into the FP16 plane; out-of-image columns store ZERO.
    #pragma unroll
    for (int fi = 0; fi < 3; ++fi) {
        if (fi < nfr) {
            const int f = (fi == 0) ? fid0 : (fi == 1) ? fid1 : fid2;
            const int q = f * 16 + col;
            const int wc = w0 - 3 + q;
            const bool vcol = ((unsigned)wc < (unsigned)WO);
            if (q < 134) {
                #pragma unroll
                for (int mf = 0; mf < 4; ++mf) {
                    if (mf < 3 || g < 2) {          // ch 56..63 don't exist
                        const int chb = mf * 16 + g * 4;
                        unsigned short hv[4];
                        #pragma unroll
                        for (int r = 0; r < 4; ++r) {
                            const float v = vcol ? (acc1[fi][mf][r] + b1p[chb + r]) : 0.f;
                            hv[r] = h_rne(v);
                        }
                        const int ip = mf * 8 + g * 2;
                        Lp[q * 28 + ip]     = ((unsigned)hv[1] << 16) | hv[0];
                        Lp[q * 28 + ip + 1] = ((unsigned)hv[3] << 16) | hv[2];
                    }
                }
            }
        }
    }
    __syncthreads();

    // ---- stage 2 (fp16): wave wv = mf; all 128 px (nf=0..7) ----------------
    const int mf2 = wv;
    f32x4 acc[8];
    #pragma unroll
    for (int nf = 0; nf < 8; ++nf)
        acc[nf] = (f32x4){0.f, 0.f, 0.f, 0.f};

    #pragma unroll
    for (int c = 0; c < 13; ++c) {
        const int kg  = 4 * c + g;
        const int oct = (kg * 37) >> 8;     // kg/7 for kg<=51
        const int t   = kg - 7 * oct;
        FragH ah;
        ah.q = wpC[(c * 4 + mf2) * 64 + lane];
        const int bqb = (col + t) * 7 + oct;
        #pragma unroll
        for (int nf = 0; nf < 8; ++nf) {
            FragH bh;
            bh.q = L4[bqb + nf * 112];      // +16 px * 7 uint4
            acc[nf] = __builtin_amdgcn_mfma_f32_16x16x32_f16(ah.v, bh.v, acc[nf], 0, 0, 0);
        }
    }

    // ---- epilogue: sq, cross-wave min, exp-weighted flow average -----------
    float bb2[4];
    #pragma unroll
    for (int r = 0; r < 4; ++r)
        bb2[r] = b2p[mf2 * 16 + g * 4 + r];

    #pragma unroll
    for (int nf = 0; nf < 8; ++nf)
        #pragma unroll
        for (int r = 0; r < 4; ++r) {
            const float fv = acc[nf][r] + bb2[r];
            acc[nf][r] = fv * fv;
        }

    #pragma unroll
    for (int nf = 0; nf < 8; ++nf) {
        float m = fminf(fminf(acc[nf][0], acc[nf][1]), fminf(acc[nf][2], acc[nf][3]));
        m = fminf(m, __shfl_xor(m, 16));
        m = fminf(m, __shfl_xor(m, 32));
        if (lane < 16) gm[wv][nf * 16 + lane] = m;
    }
    __syncthreads();

    float M[8];
    #pragma unroll
    for (int nf = 0; nf < 8; ++nf)
        M[nf] = fminf(fminf(gm[0][nf * 16 + col], gm[1][nf * 16 + col]),
                      fminf(gm[2][nf * 16 + col], gm[3][nf * 16 + col]));

    const float* fpx = flowp + (size_t)h * FP_W + (w0 + col);
    const float* fpy = fpx + (size_t)FP_W * FP_W;
    float dv[8], sx[8], sy[8];
    #pragma unroll
    for (int nf = 0; nf < 8; ++nf) { dv[nf] = 0.f; sx[nf] = 0.f; sy[nf] = 0.f; }

    #pragma unroll
    for (int r = 0; r < 4; ++r) {
        const int ch = mf2 * 16 + g * 4 + r;
        int ki = (ch * 37) >> 8;            // floor(ch/7) for ch<64
        int kj = ch - 7 * ki;
        ki = min(ki, 6);                    // pad channels: d==0, clamp for safety
        kj = min(kj, 6);
        const int off = ki * FP_W + kj;
        #pragma unroll
        for (int nf = 0; nf < 8; ++nf) {
            const float d = __expf(M[nf] - acc[nf][r]);
            dv[nf] += d;
            sx[nf] += d * fpx[off + nf * 16];
            sy[nf] += d * fpy[off + nf * 16];
        }
    }

    #pragma unroll
    for (int nf = 0; nf < 8; ++nf) {
        float d = dv[nf], x = sx[nf], y = sy[nf];
        d += __shfl_xor(d, 16);  x += __shfl_xor(x, 16);  y += __shfl_xor(y, 16);
        d += __shfl_xor(d, 32);  x += __shfl_xor(x, 32);  y += __shfl_xor(y, 32);
        if (lane < 16) {
            dvp[wv][nf * 16 + lane] = d;
            sxp[wv][nf * 16 + lane] = x;
            syp[wv][nf * 16 + lane] = y;
        }
    }
    __syncthreads();

    if (tid < 128) {
        const float D = dvp[0][tid] + dvp[1][tid] + dvp[2][tid] + dvp[3][tid];
        const float X = sxp[0][tid] + sxp[1][tid] + sxp[2][tid] + sxp[3][tid];
        const float Y = syp[0][tid] + syp[1][tid] + syp[2][tid] + syp[3][tid];
        const int w = w0 + tid;
        out[(size_t)h * WO + w]                   = X / D;
        out[(size_t)HO * WO + (size_t)h * WO + w] = Y / D;
    }
}

// ---------------------------------------------------------------------------
extern "C" void kernel_launch(void* const* d_in, const int* in_sizes, int n_in,
                              void* d_out, int out_size, void* d_ws, size_t ws_size,
                              hipStream_t stream) {
    const float* reg_feat = (const float*)d_in[0];
    const float* flow     = (const float*)d_in[1];
    const float* wt       = (const float*)d_in[2];
    const float* bt       = (const float*)d_in[3];
    const float* w1       = (const float*)d_in[4];
    const float* b1       = (const float*)d_in[5];
    const float* w2       = (const float*)d_in[6];
    const float* b2       = (const float*)d_in[7];
    float* out = (float*)d_out;
    (void)in_sizes; (void)n_in; (void)out_size; (void)ws_size;

    float*          ws   = (float*)d_ws;
    uint4*          wpC  = (uint4*)(ws + OFF_WPC);
    float*          b2p  = ws + OFF_B2P;
    uint4*          wpB  = (uint4*)(ws + OFF_WPB);
    float*          b1p  = ws + OFF_B1P;
    uint4*          wpA  = (uint4*)(ws + OFF_WPA);
    unsigned short* f0h  = (unsigned short*)(ws + OFF_F0);
    unsigned short* f0l  = f0h + (size_t)HO * WO * CI;
    unsigned short* xph  = (unsigned short*)(ws + OFF_XPP);
    unsigned short* xpl  = xph + (size_t)XP_W * XP_W * 32;
    float*          flowp = ws + OFF_FLP;

    repack<<<26, 256, 0, stream>>>(wt, w1, b1, w2, b2, wpA, wpB, b1p, wpC, b2p);

    const int padBlocks = XP_W + (2 * FP_W * FP_W + 255) / 256;
    for (int b = 0; b < 4; ++b) {
        const float* xb  = reg_feat + (size_t)b * CI * HI * WI;
        const float* flb = flow     + (size_t)b * 2 * HO * WO;
        float*       ob  = out      + (size_t)b * 2 * HO * WO;
        kPP<<<padBlocks, 256, 0, stream>>>(xb, flb, xph, xpl, flowp);
        kA<<<1024, 256, 0, stream>>>(xph, xpl, wpA, bt, f0h, f0l);
        kBC<<<2048, 256, 0, stream>>>(f0h, f0l, wpB, b1p, wpC, b2p, flowp, ob);
    }
}

// Round 19
// 260.501 us; speedup vs baseline: 2.3297x; 1.3581x over previous
//
#include <hip/hip_runtime.h>
#include <hip/hip_fp16.h>

constexpr int HI = 256, WI = 256;   // reg_feat spatial
constexpr int HO = 512, WO = 512;   // upsampled spatial
constexpr int CI = 32;              // feat channels
constexpr int CK = 49;              // 7x7 unfold channels

// ---- ws layout (float offsets) --------------------------------------------
constexpr size_t OFF_WPC = 0;                         // w2 fp16: 13*4*64 uint4 = 13312 f32
constexpr size_t OFF_B2P = 13312;                     // padded b2 [64]
constexpr size_t OFF_WPB = 13376;                     // w1 fp16: 7*4*64 uint4 = 7168 f32
constexpr size_t OFF_B1P = 20544;                     // padded b1 [64]
constexpr size_t OFF_WPA = 20608;                     // wt fp16: 4*4*2*64 uint4 = 8192 f32
constexpr size_t OFF_F0  = 28800;                     // f0p fp16 [512][512][32] (4.2M f32)
constexpr size_t OFF_XP  = OFF_F0 + (size_t)HO * WO * CI / 2;     // xp fp16 [258][258][32]
constexpr size_t OFF_FLP = OFF_XP + (size_t)258 * 258 * 32 / 2;   // flowp f32 [2][518][518]

constexpr int FP_W = 518;            // padded flow row (512 + 3 + 3)
constexpr int XP_W = 258;            // padded x row (256 + 1 + 1)

using f16x8 = __attribute__((ext_vector_type(8))) _Float16;
using f32x4 = __attribute__((ext_vector_type(4))) float;

__device__ inline unsigned short h_rne(float x) {      // fp32 -> fp16 bits (RNE)
    return __half_as_ushort(__float2half(x));
}

union FragH { uint4 q; f16x8 v; };

// ---------------------------------------------------------------------------
// kPP: x -> single fp16 plane xp [258][258][32] (zero border); flow -> flowp.
// ---------------------------------------------------------------------------
__global__ void kPP(const float* __restrict__ x, const float* __restrict__ flow,
                    unsigned short* __restrict__ xp, float* __restrict__ flowp)
{
    const int bid = blockIdx.x;
    if (bid < XP_W) {
        const int yp = bid;
        const int y  = yp - 1;
        for (int xpc = threadIdx.x; xpc < XP_W; xpc += 256) {
            const int xc = xpc - 1;
            uint4* dst = reinterpret_cast<uint4*>(xp + ((size_t)yp * XP_W + xpc) * 32);
            if ((unsigned)y < 256u && (unsigned)xc < 256u) {
                const float* src = x + y * 256 + xc;
                unsigned w[16];
                #pragma unroll
                for (int c2 = 0; c2 < 16; ++c2) {
                    const unsigned short h0 = h_rne(src[(size_t)(2 * c2) * 65536]);
                    const unsigned short h1 = h_rne(src[(size_t)(2 * c2 + 1) * 65536]);
                    w[c2] = ((unsigned)h1 << 16) | h0;
                }
                const uint4* q = reinterpret_cast<const uint4*>(w);
                #pragma unroll
                for (int r = 0; r < 4; ++r) dst[r] = q[r];
            } else {
                #pragma unroll
                for (int r = 0; r < 4; ++r) dst[r] = make_uint4(0u, 0u, 0u, 0u);
            }
        }
    } else {
        const int idx = (bid - XP_W) * 256 + threadIdx.x;
        if (idx >= 2 * FP_W * FP_W) return;
        const int p  = idx / (FP_W * FP_W);
        const int q  = idx - p * (FP_W * FP_W);
        const int hh = q / FP_W;
        const int ww = q - hh * FP_W;
        float v = 0.f;
        const int hs = hh - 3, wsx = ww - 3;
        if ((unsigned)hs < (unsigned)HO && (unsigned)wsx < (unsigned)WO)
            v = flow[p * (HO * WO) + hs * WO + wsx];
        flowp[idx] = v;
    }
}

// ---------------------------------------------------------------------------
// repack: ALL weight fragments now fp16 single-set.
//  wpA[((cls*4+tap)*2+mf)*64+lane]  (kA: chunk=tap, k=i)
//  wpB[(t*4+mf)*64+lane]            (stage-1: chunk=t, k=i)
//  wpC[(c*4+mf)*64+lane]            (stage-2: kg=4c+g -> oct,t; i=oct*8+j)
//  A-frag convention: lane l elem j -> A[mf*16+(l&15)][(l>>4)*8+j]
// ---------------------------------------------------------------------------
__global__ void repack(const float* __restrict__ wt,
                       const float* __restrict__ w1, const float* __restrict__ b1,
                       const float* __restrict__ w2, const float* __restrict__ b2,
                       uint4* __restrict__ wpA, uint4* __restrict__ wpB,
                       float* __restrict__ b1p, uint4* __restrict__ wpC,
                       float* __restrict__ b2p)
{
    const int j = blockIdx.x * 256 + threadIdx.x;
    if (j < 64) {
        b2p[j] = (j < CK) ? b2[j] : 1e18f;
        b1p[j] = (j < CK) ? b1[j] : 0.f;
    }
    if (j < 4 * 4 * 2 * 64) {               // kA fp16
        const int lane = j & 63;
        const int mf   = (j >> 6) & 1;
        const int tap  = (j >> 7) & 3;
        const int cls  = j >> 9;
        const int ohpar = cls >> 1, par = cls & 1;
        const int a = tap >> 1, d = tap & 1;
        const int kh = (ohpar ? 0 : 1) + 2 * a;
        const int kw = (par ? 0 : 1) + 2 * d;
        const int o = mf * 16 + (lane & 15);
        unsigned short b[8];
        #pragma unroll
        for (int jj = 0; jj < 8; ++jj) {
            const int i = (lane >> 4) * 8 + jj;
            b[jj] = h_rne(wt[((i * 32 + o) * 4 + kh) * 4 + kw]);
        }
        uint4 q;
        q.x = ((unsigned)b[1] << 16) | b[0];
        q.y = ((unsigned)b[3] << 16) | b[2];
        q.z = ((unsigned)b[5] << 16) | b[4];
        q.w = ((unsigned)b[7] << 16) | b[6];
        wpA[((cls * 4 + tap) * 2 + mf) * 64 + lane] = q;
    }
    if (j < 7 * 4 * 64) {                   // stage-1 fp16: chunk t, k = i
        const int lane = j & 63;
        const int mf   = (j >> 6) & 3;
        const int t    = j >> 8;
        const int o = mf * 16 + (lane & 15);
        unsigned short b[8];
        #pragma unroll
        for (int jj = 0; jj < 8; ++jj) {
            const int i = (lane >> 4) * 8 + jj;
            b[jj] = h_rne((o < CK) ? w1[o * 224 + i * 7 + t] : 0.f);
        }
        uint4 q;
        q.x = ((unsigned)b[1] << 16) | b[0];
        q.y = ((unsigned)b[3] << 16) | b[2];
        q.z = ((unsigned)b[5] << 16) | b[4];
        q.w = ((unsigned)b[7] << 16) | b[6];
        wpB[(t * 4 + mf) * 64 + lane] = q;
    }
    if (j < 13 * 4 * 64) {                  // stage-2 fp16 (R18, unchanged)
        const int c    = j >> 8;
        const int mf   = (j >> 6) & 3;
        const int lane = j & 63;
        const int o   = mf * 16 + (lane & 15);
        const int kg  = 4 * c + (lane >> 4);
        const int oct = kg / 7;
        const int t   = kg - 7 * oct;
        unsigned short b[8];
        #pragma unroll
        for (int jj = 0; jj < 8; ++jj) {
            const int i = oct * 8 + jj;
            float v = 0.f;
            if (kg < CK && o < CK && i < CK) v = w2[o * 343 + i * 7 + t];
            b[jj] = h_rne(v);
        }
        uint4 q;
        q.x = ((unsigned)b[1] << 16) | b[0];
        q.y = ((unsigned)b[3] << 16) | b[2];
        q.z = ((unsigned)b[5] << 16) | b[4];
        q.w = ((unsigned)b[7] << 16) | b[6];
        wpC[(c * 4 + mf) * 64 + lane] = q;
    }
}

// ---------------------------------------------------------------------------
// kA: ConvTranspose2d via fp16 MFMA (1 MFMA per tap x mf x nf). B-frag = one
// dwordx4 from xp; epilogue packs a single fp16 plane f0p via LDS transpose.
// ---------------------------------------------------------------------------
__global__ __launch_bounds__(256, 4)
void kA(const unsigned short* __restrict__ xp, const uint4* __restrict__ wpA,
        const float* __restrict__ bt, unsigned short* __restrict__ f0p)
{
    __shared__ unsigned ep[4][64 * 20];     // [px][16 u32 fp16-pairs + 4 pad]

    const int tid  = threadIdx.x;
    const int oh   = blockIdx.x >> 1;
    const int half = blockIdx.x & 1;
    const int wv   = tid >> 6;
    const int lane = tid & 63;
    const int col  = lane & 15;
    const int g    = lane >> 4;
    const int par  = wv >> 1;
    const int n0   = half * 128 + (wv & 1) * 64;

    const int ohpar = oh & 1;
    const int kh0   = ohpar ? 0 : 1;
    const int ihA   = (oh + 1 - kh0) >> 1;
    const int cls   = ohpar * 2 + par;
    const int ioff  = par ? 2 : 1;

    f32x4 acc[2][4];
    #pragma unroll
    for (int mf = 0; mf < 2; ++mf)
        #pragma unroll
        for (int nf = 0; nf < 4; ++nf)
            acc[mf][nf] = (f32x4){0.f, 0.f, 0.f, 0.f};

    #pragma unroll
    for (int a = 0; a < 2; ++a) {
        const int rowbase = (ihA + 1 - a) * XP_W;
        #pragma unroll
        for (int d = 0; d < 2; ++d) {
            FragH B[4];
            #pragma unroll
            for (int nf = 0; nf < 4; ++nf) {
                const size_t base =
                    ((size_t)(rowbase + n0 + nf * 16 + col + ioff - d)) * 32 + g * 8;
                B[nf].q = *reinterpret_cast<const uint4*>(xp + base);
            }
            const int tap = a * 2 + d;
            #pragma unroll
            for (int mf = 0; mf < 2; ++mf) {
                FragH ah;
                ah.q = wpA[((cls * 4 + tap) * 2 + mf) * 64 + lane];
                #pragma unroll
                for (int nf = 0; nf < 4; ++nf)
                    acc[mf][nf] = __builtin_amdgcn_mfma_f32_16x16x32_f16(ah.v, B[nf].v, acc[mf][nf], 0, 0, 0);
            }
        }
    }

    // epilogue: bias, fp16 pack, LDS transpose (wave-private), plane store
    unsigned* myep = ep[wv];
    #pragma unroll
    for (int mf = 0; mf < 2; ++mf)
        #pragma unroll
        for (int nf = 0; nf < 4; ++nf) {
            unsigned short hv[4];
            #pragma unroll
            for (int r = 0; r < 4; ++r) {
                const int ch = mf * 16 + g * 4 + r;
                hv[r] = h_rne(acc[mf][nf][r] + bt[ch]);
            }
            unsigned* row = myep + (nf * 16 + col) * 20;
            const int cp = mf * 8 + g * 2;
            row[cp]     = ((unsigned)hv[1] << 16) | hv[0];
            row[cp + 1] = ((unsigned)hv[3] << 16) | hv[2];
        }
    // same-wave LDS RAW: compiler orders via lgkmcnt; no barrier needed

    const int ow = 2 * (n0 + lane) + par;
    uint4* dst = reinterpret_cast<uint4*>(f0p + ((size_t)oh * WO + ow) * 32);
    const uint4* src = reinterpret_cast<const uint4*>(myep + lane * 20);
    #pragma unroll
    for (int u = 0; u < 4; ++u) dst[u] = src[u];
}

// ---------------------------------------------------------------------------
// kBC: FUSED stage B + stage C, all fp16 MFMA. Stage 1: 1 MFMA per
// (t, fi, mf), B-frag = one dwordx4 from f0p. Stage 2 unchanged from R18.
// ---------------------------------------------------------------------------
__global__ __launch_bounds__(256, 4)
void kBC(const unsigned short* __restrict__ f0p, const uint4* __restrict__ wpB,
         const float* __restrict__ b1p, const uint4* __restrict__ wpC,
         const float* __restrict__ b2p, const float* __restrict__ flowp,
         float* __restrict__ out)
{
    __shared__ uint4 L4[134 * 7];           // fp16 plane, rows of 7 uint4 (56 ch)
    __shared__ float gm[4][128];            // per-wave per-pixel min partials
    __shared__ float dvp[4][128];           // per-wave softmax partials
    __shared__ float sxp[4][128];
    __shared__ float syp[4][128];
    unsigned* Lp = reinterpret_cast<unsigned*>(L4);

    // bijective XCD swizzle: 2048 blocks = 8 XCDs x 256 contiguous
    const int bid = ((blockIdx.x & 7) << 8) + (blockIdx.x >> 3);
    const int h   = bid >> 2;
    const int w0  = (bid & 3) << 7;

    const int tid  = threadIdx.x;
    const int wv   = tid >> 6;
    const int lane = tid & 63;
    const int col  = lane & 15;
    const int g    = lane >> 4;

    // ---- stage 1: f1 row h, cols w0-3 .. w0+140 (9 frags of 16) ------------
    const int nfr = (wv == 3) ? 3 : 2;
    const int fid0 = wv, fid1 = wv + 4, fid2 = 8;

    f32x4 acc1[3][4];
    #pragma unroll
    for (int fi = 0; fi < 3; ++fi)
        #pragma unroll
        for (int mf = 0; mf < 4; ++mf)
            acc1[fi][mf] = (f32x4){0.f, 0.f, 0.f, 0.f};

    #pragma unroll
    for (int t = 0; t < 7; ++t) {
        const int hr = h + t - 3;
        if ((unsigned)hr < (unsigned)HO) {
            FragH ah[4];
            #pragma unroll
            for (int mf = 0; mf < 4; ++mf)
                ah[mf].q = wpB[(t * 4 + mf) * 64 + lane];
            #pragma unroll
            for (int fi = 0; fi < 3; ++fi) {
                if (fi < nfr) {
                    const int f  = (fi == 0) ? fid0 : (fi == 1) ? fid1 : fid2;
                    const int wc = w0 - 3 + f * 16 + col;
                    const int wcc = min(max(wc, 0), WO - 1);
                    const bool valid = ((unsigned)wc < (unsigned)WO);
                    const size_t base = ((size_t)hr * WO + wcc) * 32 + g * 8;
                    FragH bf;
                    bf.q = *reinterpret_cast<const uint4*>(f0p + base);
                    if (!valid) bf.q = make_uint4(0u, 0u, 0u, 0u);
                    #pragma unroll
                    for (int mf = 0; mf < 4; ++mf)
                        acc1[fi][mf] = __builtin_amdgcn_mfma_f32_16x16x32_f16(ah[mf].v, bf.v, acc1[fi][mf], 0, 0, 0);
                }
            }
        }
    }

    // write f1 row into the FP16 plane; out-of-image columns store ZERO.
    #pragma unroll
    for (int fi = 0; fi < 3; ++fi) {
        if (fi < nfr) {
            const int f = (fi == 0) ? fid0 : (fi == 1) ? fid1 : fid2;
            const int q = f * 16 + col;
            const int wc = w0 - 3 + q;
            const bool vcol = ((unsigned)wc < (unsigned)WO);
            if (q < 134) {
                #pragma unroll
                for (int mf = 0; mf < 4; ++mf) {
                    if (mf < 3 || g < 2) {          // ch 56..63 don't exist
                        const int chb = mf * 16 + g * 4;
                        unsigned short hv[4];
                        #pragma unroll
                        for (int r = 0; r < 4; ++r) {
                            const float v = vcol ? (acc1[fi][mf][r] + b1p[chb + r]) : 0.f;
                            hv[r] = h_rne(v);
                        }
                        const int ip = mf * 8 + g * 2;
                        Lp[q * 28 + ip]     = ((unsigned)hv[1] << 16) | hv[0];
                        Lp[q * 28 + ip + 1] = ((unsigned)hv[3] << 16) | hv[2];
                    }
                }
            }
        }
    }
    __syncthreads();

    // ---- stage 2 (fp16): wave wv = mf; all 128 px (nf=0..7) ----------------
    const int mf2 = wv;
    f32x4 acc[8];
    #pragma unroll
    for (int nf = 0; nf < 8; ++nf)
        acc[nf] = (f32x4){0.f, 0.f, 0.f, 0.f};

    #pragma unroll
    for (int c = 0; c < 13; ++c) {
        const int kg  = 4 * c + g;
        const int oct = (kg * 37) >> 8;     // kg/7 for kg<=51
        const int t   = kg - 7 * oct;
        FragH ah;
        ah.q = wpC[(c * 4 + mf2) * 64 + lane];
        const int bqb = (col + t) * 7 + oct;
        #pragma unroll
        for (int nf = 0; nf < 8; ++nf) {
            FragH bh;
            bh.q = L4[bqb + nf * 112];      // +16 px * 7 uint4
            acc[nf] = __builtin_amdgcn_mfma_f32_16x16x32_f16(ah.v, bh.v, acc[nf], 0, 0, 0);
        }
    }

    // ---- epilogue: sq, cross-wave min, exp-weighted flow average -----------
    float bb2[4];
    #pragma unroll
    for (int r = 0; r < 4; ++r)
        bb2[r] = b2p[mf2 * 16 + g * 4 + r];

    #pragma unroll
    for (int nf = 0; nf < 8; ++nf)
        #pragma unroll
        for (int r = 0; r < 4; ++r) {
            const float fv = acc[nf][r] + bb2[r];
            acc[nf][r] = fv * fv;
        }

    #pragma unroll
    for (int nf = 0; nf < 8; ++nf) {
        float m = fminf(fminf(acc[nf][0], acc[nf][1]), fminf(acc[nf][2], acc[nf][3]));
        m = fminf(m, __shfl_xor(m, 16));
        m = fminf(m, __shfl_xor(m, 32));
        if (lane < 16) gm[wv][nf * 16 + lane] = m;
    }
    __syncthreads();

    float M[8];
    #pragma unroll
    for (int nf = 0; nf < 8; ++nf)
        M[nf] = fminf(fminf(gm[0][nf * 16 + col], gm[1][nf * 16 + col]),
                      fminf(gm[2][nf * 16 + col], gm[3][nf * 16 + col]));

    const float* fpx = flowp + (size_t)h * FP_W + (w0 + col);
    const float* fpy = fpx + (size_t)FP_W * FP_W;
    float dv[8], sx[8], sy[8];
    #pragma unroll
    for (int nf = 0; nf < 8; ++nf) { dv[nf] = 0.f; sx[nf] = 0.f; sy[nf] = 0.f; }

    #pragma unroll
    for (int r = 0; r < 4; ++r) {
        const int ch = mf2 * 16 + g * 4 + r;
        int ki = (ch * 37) >> 8;            // floor(ch/7) for ch<64
        int kj = ch - 7 * ki;
        ki = min(ki, 6);                    // pad channels: d==0, clamp for safety
        kj = min(kj, 6);
        const int off = ki * FP_W + kj;
        #pragma unroll
        for (int nf = 0; nf < 8; ++nf) {
            const float d = __expf(M[nf] - acc[nf][r]);
            dv[nf] += d;
            sx[nf] += d * fpx[off + nf * 16];
            sy[nf] += d * fpy[off + nf * 16];
        }
    }

    #pragma unroll
    for (int nf = 0; nf < 8; ++nf) {
        float d = dv[nf], x = sx[nf], y = sy[nf];
        d += __shfl_xor(d, 16);  x += __shfl_xor(x, 16);  y += __shfl_xor(y, 16);
        d += __shfl_xor(d, 32);  x += __shfl_xor(x, 32);  y += __shfl_xor(y, 32);
        if (lane < 16) {
            dvp[wv][nf * 16 + lane] = d;
            sxp[wv][nf * 16 + lane] = x;
            syp[wv][nf * 16 + lane] = y;
        }
    }
    __syncthreads();

    if (tid < 128) {
        const float D = dvp[0][tid] + dvp[1][tid] + dvp[2][tid] + dvp[3][tid];
        const float X = sxp[0][tid] + sxp[1][tid] + sxp[2][tid] + sxp[3][tid];
        const float Y = syp[0][tid] + syp[1][tid] + syp[2][tid] + syp[3][tid];
        const int w = w0 + tid;
        out[(size_t)h * WO + w]                   = X / D;
        out[(size_t)HO * WO + (size_t)h * WO + w] = Y / D;
    }
}

// ---------------------------------------------------------------------------
extern "C" void kernel_launch(void* const* d_in, const int* in_sizes, int n_in,
                              void* d_out, int out_size, void* d_ws, size_t ws_size,
                              hipStream_t stream) {
    const float* reg_feat = (const float*)d_in[0];
    const float* flow     = (const float*)d_in[1];
    const float* wt       = (const float*)d_in[2];
    const float* bt       = (const float*)d_in[3];
    const float* w1       = (const float*)d_in[4];
    const float* b1       = (const float*)d_in[5];
    const float* w2       = (const float*)d_in[6];
    const float* b2       = (const float*)d_in[7];
    float* out = (float*)d_out;
    (void)in_sizes; (void)n_in; (void)out_size; (void)ws_size;

    float*          ws    = (float*)d_ws;
    uint4*          wpC   = (uint4*)(ws + OFF_WPC);
    float*          b2p   = ws + OFF_B2P;
    uint4*          wpB   = (uint4*)(ws + OFF_WPB);
    float*          b1p   = ws + OFF_B1P;
    uint4*          wpA   = (uint4*)(ws + OFF_WPA);
    unsigned short* f0p   = (unsigned short*)(ws + OFF_F0);
    unsigned short* xp    = (unsigned short*)(ws + OFF_XP);
    float*          flowp = ws + OFF_FLP;

    repack<<<26, 256, 0, stream>>>(wt, w1, b1, w2, b2, wpA, wpB, b1p, wpC, b2p);

    const int padBlocks = XP_W + (2 * FP_W * FP_W + 255) / 256;
    for (int b = 0; b < 4; ++b) {
        const float* xb  = reg_feat + (size_t)b * CI * HI * WI;
        const float* flb = flow     + (size_t)b * 2 * HO * WO;
        float*       ob  = out      + (size_t)b * 2 * HO * WO;
        kPP<<<padBlocks, 256, 0, stream>>>(xb, flb, xp, flowp);
        kA<<<1024, 256, 0, stream>>>(xp, wpA, bt, f0p);
        kBC<<<2048, 256, 0, stream>>>(f0p, wpB, b1p, wpC, b2p, flowp, ob);
    }
}

// Round 20
// 259.190 us; speedup vs baseline: 2.3415x; 1.0051x over previous
//
#include <hip/hip_runtime.h>
#include <hip/hip_fp16.h>

constexpr int HI = 256, WI = 256;   // reg_feat spatial
constexpr int HO = 512, WO = 512;   // upsampled spatial
constexpr int CI = 32;              // feat channels
constexpr int CK = 49;              // 7x7 unfold channels

// ---- ws layout (float offsets) --------------------------------------------
constexpr size_t OFF_WPC = 0;                         // w2 fp16 32x32: 26*2*64 uint4 = 13312 f32
constexpr size_t OFF_B2P = 13312;                     // padded b2 [64]
constexpr size_t OFF_WPB = 13376;                     // w1 fp16: 7*4*64 uint4 = 7168 f32
constexpr size_t OFF_B1P = 20544;                     // padded b1 [64]
constexpr size_t OFF_WPA = 20608;                     // wt fp16: 4*4*2*64 uint4 = 8192 f32
constexpr size_t OFF_F0  = 28800;                     // f0p fp16 [512][512][32]
constexpr size_t OFF_XP  = OFF_F0 + (size_t)HO * WO * CI / 2;     // xp fp16 [258][258][32]
constexpr size_t OFF_FLP = OFF_XP + (size_t)258 * 258 * 32 / 2;   // flowp f32 [2][518][518]

constexpr int FP_W = 518;            // padded flow row (512 + 3 + 3)
constexpr int XP_W = 258;            // padded x row (256 + 1 + 1)

using f16x8  = __attribute__((ext_vector_type(8))) _Float16;
using f32x4  = __attribute__((ext_vector_type(4))) float;
using f32x16 = __attribute__((ext_vector_type(16))) float;

__device__ inline unsigned short h_rne(float x) {      // fp32 -> fp16 bits (RNE)
    return __half_as_ushort(__float2half(x));
}

union FragH { uint4 q; f16x8 v; };

// ---------------------------------------------------------------------------
// kPP: x -> single fp16 plane xp [258][258][32] (zero border); flow -> flowp.
// (unchanged R19)
// ---------------------------------------------------------------------------
__global__ void kPP(const float* __restrict__ x, const float* __restrict__ flow,
                    unsigned short* __restrict__ xp, float* __restrict__ flowp)
{
    const int bid = blockIdx.x;
    if (bid < XP_W) {
        const int yp = bid;
        const int y  = yp - 1;
        for (int xpc = threadIdx.x; xpc < XP_W; xpc += 256) {
            const int xc = xpc - 1;
            uint4* dst = reinterpret_cast<uint4*>(xp + ((size_t)yp * XP_W + xpc) * 32);
            if ((unsigned)y < 256u && (unsigned)xc < 256u) {
                const float* src = x + y * 256 + xc;
                unsigned w[16];
                #pragma unroll
                for (int c2 = 0; c2 < 16; ++c2) {
                    const unsigned short h0 = h_rne(src[(size_t)(2 * c2) * 65536]);
                    const unsigned short h1 = h_rne(src[(size_t)(2 * c2 + 1) * 65536]);
                    w[c2] = ((unsigned)h1 << 16) | h0;
                }
                const uint4* q = reinterpret_cast<const uint4*>(w);
                #pragma unroll
                for (int r = 0; r < 4; ++r) dst[r] = q[r];
            } else {
                #pragma unroll
                for (int r = 0; r < 4; ++r) dst[r] = make_uint4(0u, 0u, 0u, 0u);
            }
        }
    } else {
        const int idx = (bid - XP_W) * 256 + threadIdx.x;
        if (idx >= 2 * FP_W * FP_W) return;
        const int p  = idx / (FP_W * FP_W);
        const int q  = idx - p * (FP_W * FP_W);
        const int hh = q / FP_W;
        const int ww = q - hh * FP_W;
        float v = 0.f;
        const int hs = hh - 3, wsx = ww - 3;
        if ((unsigned)hs < (unsigned)HO && (unsigned)wsx < (unsigned)WO)
            v = flow[p * (HO * WO) + hs * WO + wsx];
        flowp[idx] = v;
    }
}

// ---------------------------------------------------------------------------
// repack: wpA/wpB fp16 (R19, unchanged). wpC now fp16 in the 32x32 encoding
// (validated R12): A-frag lane l elem j -> A[row=l&31][k=cc*16+(l>>5)*8+j],
// channel o = m*32+row; kg=2cc+(l>>5) -> oct=kg/7, t=kg%7, i=oct*8+j.
// Index: wpC[(cc*2+m)*64+lane], cc<26.
// ---------------------------------------------------------------------------
__global__ void repack(const float* __restrict__ wt,
                       const float* __restrict__ w1, const float* __restrict__ b1,
                       const float* __restrict__ w2, const float* __restrict__ b2,
                       uint4* __restrict__ wpA, uint4* __restrict__ wpB,
                       float* __restrict__ b1p, uint4* __restrict__ wpC,
                       float* __restrict__ b2p)
{
    const int j = blockIdx.x * 256 + threadIdx.x;
    if (j < 64) {
        b2p[j] = (j < CK) ? b2[j] : 1e18f;
        b1p[j] = (j < CK) ? b1[j] : 0.f;
    }
    if (j < 4 * 4 * 2 * 64) {               // kA fp16 (unchanged R19)
        const int lane = j & 63;
        const int mf   = (j >> 6) & 1;
        const int tap  = (j >> 7) & 3;
        const int cls  = j >> 9;
        const int ohpar = cls >> 1, par = cls & 1;
        const int a = tap >> 1, d = tap & 1;
        const int kh = (ohpar ? 0 : 1) + 2 * a;
        const int kw = (par ? 0 : 1) + 2 * d;
        const int o = mf * 16 + (lane & 15);
        unsigned short b[8];
        #pragma unroll
        for (int jj = 0; jj < 8; ++jj) {
            const int i = (lane >> 4) * 8 + jj;
            b[jj] = h_rne(wt[((i * 32 + o) * 4 + kh) * 4 + kw]);
        }
        uint4 q;
        q.x = ((unsigned)b[1] << 16) | b[0];
        q.y = ((unsigned)b[3] << 16) | b[2];
        q.z = ((unsigned)b[5] << 16) | b[4];
        q.w = ((unsigned)b[7] << 16) | b[6];
        wpA[((cls * 4 + tap) * 2 + mf) * 64 + lane] = q;
    }
    if (j < 7 * 4 * 64) {                   // stage-1 fp16 (unchanged R19)
        const int lane = j & 63;
        const int mf   = (j >> 6) & 3;
        const int t    = j >> 8;
        const int o = mf * 16 + (lane & 15);
        unsigned short b[8];
        #pragma unroll
        for (int jj = 0; jj < 8; ++jj) {
            const int i = (lane >> 4) * 8 + jj;
            b[jj] = h_rne((o < CK) ? w1[o * 224 + i * 7 + t] : 0.f);
        }
        uint4 q;
        q.x = ((unsigned)b[1] << 16) | b[0];
        q.y = ((unsigned)b[3] << 16) | b[2];
        q.z = ((unsigned)b[5] << 16) | b[4];
        q.w = ((unsigned)b[7] << 16) | b[6];
        wpB[(t * 4 + mf) * 64 + lane] = q;
    }
    if (j < 26 * 2 * 64) {                  // stage-2 fp16, 32x32 encoding
        const int lane = j & 63;
        const int m    = (j >> 6) & 1;
        const int cc   = j >> 7;
        const int o    = m * 32 + (lane & 31);
        const int kg   = cc * 2 + (lane >> 5);
        const int oct  = kg / 7;
        const int t    = kg - 7 * oct;
        unsigned short b[8];
        #pragma unroll
        for (int jj = 0; jj < 8; ++jj) {
            const int i = oct * 8 + jj;
            float v = 0.f;
            if (kg < CK && o < CK && i < CK) v = w2[o * 343 + i * 7 + t];
            b[jj] = h_rne(v);
        }
        uint4 q;
        q.x = ((unsigned)b[1] << 16) | b[0];
        q.y = ((unsigned)b[3] << 16) | b[2];
        q.z = ((unsigned)b[5] << 16) | b[4];
        q.w = ((unsigned)b[7] << 16) | b[6];
        wpC[(cc * 2 + m) * 64 + lane] = q;
    }
}

// ---------------------------------------------------------------------------
// kA: ConvTranspose2d via fp16 MFMA (unchanged R19).
// ---------------------------------------------------------------------------
__global__ __launch_bounds__(256, 4)
void kA(const unsigned short* __restrict__ xp, const uint4* __restrict__ wpA,
        const float* __restrict__ bt, unsigned short* __restrict__ f0p)
{
    __shared__ unsigned ep[4][64 * 20];     // [px][16 u32 fp16-pairs + 4 pad]

    const int tid  = threadIdx.x;
    const int oh   = blockIdx.x >> 1;
    const int half = blockIdx.x & 1;
    const int wv   = tid >> 6;
    const int lane = tid & 63;
    const int col  = lane & 15;
    const int g    = lane >> 4;
    const int par  = wv >> 1;
    const int n0   = half * 128 + (wv & 1) * 64;

    const int ohpar = oh & 1;
    const int kh0   = ohpar ? 0 : 1;
    const int ihA   = (oh + 1 - kh0) >> 1;
    const int cls   = ohpar * 2 + par;
    const int ioff  = par ? 2 : 1;

    f32x4 acc[2][4];
    #pragma unroll
    for (int mf = 0; mf < 2; ++mf)
        #pragma unroll
        for (int nf = 0; nf < 4; ++nf)
            acc[mf][nf] = (f32x4){0.f, 0.f, 0.f, 0.f};

    #pragma unroll
    for (int a = 0; a < 2; ++a) {
        const int rowbase = (ihA + 1 - a) * XP_W;
        #pragma unroll
        for (int d = 0; d < 2; ++d) {
            FragH B[4];
            #pragma unroll
            for (int nf = 0; nf < 4; ++nf) {
                const size_t base =
                    ((size_t)(rowbase + n0 + nf * 16 + col + ioff - d)) * 32 + g * 8;
                B[nf].q = *reinterpret_cast<const uint4*>(xp + base);
            }
            const int tap = a * 2 + d;
            #pragma unroll
            for (int mf = 0; mf < 2; ++mf) {
                FragH ah;
                ah.q = wpA[((cls * 4 + tap) * 2 + mf) * 64 + lane];
                #pragma unroll
                for (int nf = 0; nf < 4; ++nf)
                    acc[mf][nf] = __builtin_amdgcn_mfma_f32_16x16x32_f16(ah.v, B[nf].v, acc[mf][nf], 0, 0, 0);
            }
        }
    }

    unsigned* myep = ep[wv];
    #pragma unroll
    for (int mf = 0; mf < 2; ++mf)
        #pragma unroll
        for (int nf = 0; nf < 4; ++nf) {
            unsigned short hv[4];
            #pragma unroll
            for (int r = 0; r < 4; ++r) {
                const int ch = mf * 16 + g * 4 + r;
                hv[r] = h_rne(acc[mf][nf][r] + bt[ch]);
            }
            unsigned* row = myep + (nf * 16 + col) * 20;
            const int cp = mf * 8 + g * 2;
            row[cp]     = ((unsigned)hv[1] << 16) | hv[0];
            row[cp + 1] = ((unsigned)hv[3] << 16) | hv[2];
        }
    // same-wave LDS RAW: compiler orders via lgkmcnt; no barrier needed

    const int ow = 2 * (n0 + lane) + par;
    uint4* dst = reinterpret_cast<uint4*>(f0p + ((size_t)oh * WO + ow) * 32);
    const uint4* src = reinterpret_cast<const uint4*>(myep + lane * 20);
    #pragma unroll
    for (int u = 0; u < 4; ++u) dst[u] = src[u];
}

// ---------------------------------------------------------------------------
// kBC: FUSED stage B + stage C. Stage 1 fp16 (unchanged R19). Stage 2 now
// 32x32x16 fp16 (R12-validated structure): wave (wv_m,wv_n) = 32 ch x 64 px;
// B-frag = ONE ds_read_b128 shared across 32 M-rows -> stage-2 LDS reads
// halve (416 -> 200 per block). Epilogue = R12's 2-way cross-wave reduce.
// ---------------------------------------------------------------------------
__global__ __launch_bounds__(256, 4)
void kBC(const unsigned short* __restrict__ f0p, const uint4* __restrict__ wpB,
         const float* __restrict__ b1p, const uint4* __restrict__ wpC,
         const float* __restrict__ b2p, const float* __restrict__ flowp,
         float* __restrict__ out)
{
    __shared__ uint4 L4[134 * 7];           // fp16 plane, rows of 7 uint4 (56 ch)
    __shared__ float gm[2][128];            // per-m-half per-pixel min partials
    __shared__ float dvp[2][128];           // per-m-half softmax partials
    __shared__ float sxp[2][128];
    __shared__ float syp[2][128];
    unsigned* Lp = reinterpret_cast<unsigned*>(L4);

    // bijective XCD swizzle: 2048 blocks = 8 XCDs x 256 contiguous
    const int bid = ((blockIdx.x & 7) << 8) + (blockIdx.x >> 3);
    const int h   = bid >> 2;
    const int w0  = (bid & 3) << 7;

    const int tid  = threadIdx.x;
    const int wv   = tid >> 6;
    const int lane = tid & 63;
    const int col  = lane & 15;
    const int g    = lane >> 4;

    // ---- stage 1: f1 row h, cols w0-3 .. w0+140 (9 frags of 16) ------------
    const int nfr = (wv == 3) ? 3 : 2;
    const int fid0 = wv, fid1 = wv + 4, fid2 = 8;

    f32x4 acc1[3][4];
    #pragma unroll
    for (int fi = 0; fi < 3; ++fi)
        #pragma unroll
        for (int mf = 0; mf < 4; ++mf)
            acc1[fi][mf] = (f32x4){0.f, 0.f, 0.f, 0.f};

    #pragma unroll
    for (int t = 0; t < 7; ++t) {
        const int hr = h + t - 3;
        if ((unsigned)hr < (unsigned)HO) {
            FragH ah[4];
            #pragma unroll
            for (int mf = 0; mf < 4; ++mf)
                ah[mf].q = wpB[(t * 4 + mf) * 64 + lane];
            #pragma unroll
            for (int fi = 0; fi < 3; ++fi) {
                if (fi < nfr) {
                    const int f  = (fi == 0) ? fid0 : (fi == 1) ? fid1 : fid2;
                    const int wc = w0 - 3 + f * 16 + col;
                    const int wcc = min(max(wc, 0), WO - 1);
                    const bool valid = ((unsigned)wc < (unsigned)WO);
                    const size_t base = ((size_t)hr * WO + wcc) * 32 + g * 8;
                    FragH bf;
                    bf.q = *reinterpret_cast<const uint4*>(f0p + base);
                    if (!valid) bf.q = make_uint4(0u, 0u, 0u, 0u);
                    #pragma unroll
                    for (int mf = 0; mf < 4; ++mf)
                        acc1[fi][mf] = __builtin_amdgcn_mfma_f32_16x16x32_f16(ah[mf].v, bf.v, acc1[fi][mf], 0, 0, 0);
                }
            }
        }
    }

    // write f1 row into the FP16 plane; out-of-image columns store ZERO.
    #pragma unroll
    for (int fi = 0; fi < 3; ++fi) {
        if (fi < nfr) {
            const int f = (fi == 0) ? fid0 : (fi == 1) ? fid1 : fid2;
            const int q = f * 16 + col;
            const int wc = w0 - 3 + q;
            const bool vcol = ((unsigned)wc < (unsigned)WO);
            if (q < 134) {
                #pragma unroll
                for (int mf = 0; mf < 4; ++mf) {
                    if (mf < 3 || g < 2) {          // ch 56..63 don't exist
                        const int chb = mf * 16 + g * 4;
                        unsigned short hv[4];
                        #pragma unroll
                        for (int r = 0; r < 4; ++r) {
                            const float v = vcol ? (acc1[fi][mf][r] + b1p[chb + r]) : 0.f;
                            hv[r] = h_rne(v);
                        }
                        const int ip = mf * 8 + g * 2;
                        Lp[q * 28 + ip]     = ((unsigned)hv[1] << 16) | hv[0];
                        Lp[q * 28 + ip + 1] = ((unsigned)hv[3] << 16) | hv[2];
                    }
                }
            }
        }
    }
    __syncthreads();

    // ---- stage 2 (32x32x16 fp16): wave (wv_m, wv_n) = 32 ch x 64 px --------
    const int wv_m = wv >> 1;
    const int wv_n = wv & 1;
    const int lh   = lane >> 5;             // k-half selector
    const int p32  = lane & 31;             // pixel within 32-frag

    f32x16 acc2[2];
    #pragma unroll
    for (int nf = 0; nf < 2; ++nf)
        #pragma unroll
        for (int r = 0; r < 16; ++r)
            acc2[nf][r] = 0.f;

    #pragma unroll
    for (int cc = 0; cc < 25; ++cc) {       // cc=25 would be all-pad (kg 50,51)
        const int kg  = cc * 2 + lh;
        const int oct = (kg * 37) >> 8;     // kg/7 for kg<=51
        const int t   = kg - 7 * oct;
        FragH ah;
        ah.q = wpC[(cc * 2 + wv_m) * 64 + lane];
        const int bq = (wv_n * 64 + p32 + t) * 7 + oct;
        #pragma unroll
        for (int nf = 0; nf < 2; ++nf) {
            FragH bh;
            bh.q = L4[bq + nf * 224];       // +32 px * 7 uint4
            acc2[nf] = __builtin_amdgcn_mfma_f32_32x32x16_f16(ah.v, bh.v, acc2[nf], 0, 0, 0);
        }
    }

    // ---- epilogue (R12-validated): sq, 2-way min, flow average -------------
    // C/D: col(px) = lane&31, row(ch in 32) = (reg&3) + 8*(reg>>2) + 4*lh
    float bb2[16];
    #pragma unroll
    for (int reg = 0; reg < 16; ++reg) {
        const int ch = wv_m * 32 + lh * 4 + (reg & 3) + 8 * (reg >> 2);
        bb2[reg] = b2p[ch];
    }

    #pragma unroll
    for (int nf = 0; nf < 2; ++nf)
        #pragma unroll
        for (int reg = 0; reg < 16; ++reg) {
            const float fv = acc2[nf][reg] + bb2[reg];
            acc2[nf][reg] = fv * fv;
        }

    #pragma unroll
    for (int nf = 0; nf < 2; ++nf) {
        float m = acc2[nf][0];
        #pragma unroll
        for (int reg = 1; reg < 16; ++reg) m = fminf(m, acc2[nf][reg]);
        m = fminf(m, __shfl_xor(m, 32));
        if (lane < 32) gm[wv_m][wv_n * 64 + nf * 32 + lane] = m;
    }
    __syncthreads();

    float M2[2];
    #pragma unroll
    for (int nf = 0; nf < 2; ++nf) {
        const int px = wv_n * 64 + nf * 32 + p32;
        M2[nf] = fminf(gm[0][px], gm[1][px]);
    }

    const float* fpx = flowp + (size_t)h * FP_W + (w0 + wv_n * 64 + p32);
    const float* fpy = fpx + (size_t)FP_W * FP_W;
    float dv[2] = {0.f, 0.f}, sx[2] = {0.f, 0.f}, sy[2] = {0.f, 0.f};

    #pragma unroll
    for (int reg = 0; reg < 16; ++reg) {
        const int ch = wv_m * 32 + lh * 4 + (reg & 3) + 8 * (reg >> 2);
        int ki = (ch * 37) >> 8;            // floor(ch/7) for ch<64
        int kj = ch - 7 * ki;
        ki = min(ki, 6);                    // pad channels: d==0, clamp for safety
        kj = min(kj, 6);
        const int off = ki * FP_W + kj;
        #pragma unroll
        for (int nf = 0; nf < 2; ++nf) {
            const float d = __expf(M2[nf] - acc2[nf][reg]);
            dv[nf] += d;
            sx[nf] += d * fpx[off + nf * 32];
            sy[nf] += d * fpy[off + nf * 32];
        }
    }

    #pragma unroll
    for (int nf = 0; nf < 2; ++nf) {
        float d = dv[nf], x = sx[nf], y = sy[nf];
        d += __shfl_xor(d, 32);  x += __shfl_xor(x, 32);  y += __shfl_xor(y, 32);
        if (lane < 32) {
            const int px = wv_n * 64 + nf * 32 + lane;
            dvp[wv_m][px] = d;
            sxp[wv_m][px] = x;
            syp[wv_m][px] = y;
        }
    }
    __syncthreads();

    if (tid < 128) {
        const float D = dvp[0][tid] + dvp[1][tid];
        const float X = sxp[0][tid] + sxp[1][tid];
        const float Y = syp[0][tid] + syp[1][tid];
        const int w = w0 + tid;
        out[(size_t)h * WO + w]                   = X / D;
        out[(size_t)HO * WO + (size_t)h * WO + w] = Y / D;
    }
}

// ---------------------------------------------------------------------------
extern "C" void kernel_launch(void* const* d_in, const int* in_sizes, int n_in,
                              void* d_out, int out_size, void* d_ws, size_t ws_size,
                              hipStream_t stream) {
    const float* reg_feat = (const float*)d_in[0];
    const float* flow     = (const float*)d_in[1];
    const float* wt       = (const float*)d_in[2];
    const float* bt       = (const float*)d_in[3];
    const float* w1       = (const float*)d_in[4];
    const float* b1       = (const float*)d_in[5];
    const float* w2       = (const float*)d_in[6];
    const float* b2       = (const float*)d_in[7];
    float* out = (float*)d_out;
    (void)in_sizes; (void)n_in; (void)out_size; (void)ws_size;

    float*          ws    = (float*)d_ws;
    uint4*          wpC   = (uint4*)(ws + OFF_WPC);
    float*          b2p   = ws + OFF_B2P;
    uint4*          wpB   = (uint4*)(ws + OFF_WPB);
    float*          b1p   = ws + OFF_B1P;
    uint4*          wpA   = (uint4*)(ws + OFF_WPA);
    unsigned short* f0p   = (unsigned short*)(ws + OFF_F0);
    unsigned short* xp    = (unsigned short*)(ws + OFF_XP);
    float*          flowp = ws + OFF_FLP;

    repack<<<26, 256, 0, stream>>>(wt, w1, b1, w2, b2, wpA, wpB, b1p, wpC, b2p);

    const int padBlocks = XP_W + (2 * FP_W * FP_W + 255) / 256;
    for (int b = 0; b < 4; ++b) {
        const float* xb  = reg_feat + (size_t)b * CI * HI * WI;
        const float* flb = flow     + (size_t)b * 2 * HO * WO;
        float*       ob  = out      + (size_t)b * 2 * HO * WO;
        kPP<<<padBlocks, 256, 0, stream>>>(xb, flb, xp, flowp);
        kA<<<1024, 256, 0, stream>>>(xp, wpA, bt, f0p);
        kBC<<<2048, 256, 0, stream>>>(f0p, wpB, b1p, wpC, b2p, flowp, ob);
    }
}